// Round 6
// baseline (669.249 us; speedup 1.0000x reference)
//
#include <hip/hip_runtime.h>

#define LK   50      // look_back
#define NOUT 3
#define FF   64      // feature_num
#define BB   2048    // batch
#define HH   128     // units
#define BT   8       // batch rows per workgroup
#define NWG  (BB/BT) // 256 workgroups
#define NTHR 1024    // 16 waves

typedef unsigned short u16;
typedef unsigned int   u32;
typedef __attribute__((ext_vector_type(8))) short short8;
typedef __attribute__((ext_vector_type(4))) float f32x4;

#define MFMA16(a,b,c) __builtin_amdgcn_mfma_f32_16x16x32_bf16(a,b,c,0,0,0)

// pre-converted bf16 buffers (device globals; rewritten every launch)
__device__ u16 g_xbf [(size_t)BB*LK*FF];   // x,        [b][t][f]
__device__ u16 g_awT [(size_t)LK*64*192];  // attn_w^T, [t][c][k]  k:[xt(64)|h(128)]
__device__ u16 g_eW  [512*192];            // enc LSTM, [gate][k]  k:[xin(64)|h(128)]
__device__ u16 g_dW  [512*384];            // dec LSTM, [gate][k]  k:[ctx(128)|h(128)|h(128)]
__device__ u16 g_ddwT[NOUT*128*256];       // dd_w^T,   [s][n][k]  k:[enc(128)|h(128)]
__device__ u16 g_fcwT[NOUT*64*128];        // fc_w^T,   [s][n][k]
__device__ u16 g_encbf[(size_t)BB*LK*256]; // encoder outputs hi/lo: [b][t][hi(128)|lo(128)]

__device__ __forceinline__ float sigf(float x) { return 1.0f / (1.0f + __expf(-x)); }
__device__ __forceinline__ float tanhff(float x) { return 1.0f - 2.0f / (__expf(2.0f * x) + 1.0f); }
__device__ __forceinline__ u16 f2b(float f) {
    union { float f; u32 u; } v; v.f = f;
    u32 r = v.u + 0x7fffu + ((v.u >> 16) & 1u);
    return (u16)(r >> 16);
}
__device__ __forceinline__ float b2f(u16 h) {
    union { u32 u; float f; } v; v.u = ((u32)h) << 16; return v.f;
}

// R3's known-good convert kernel (verbatim; g_encbf untouched here)
__global__ __launch_bounds__(256)
void convert_kernel(const float* __restrict__ x,
                    const float* __restrict__ eWih, const float* __restrict__ eWhh,
                    const float* __restrict__ aw,
                    const float* __restrict__ dWih, const float* __restrict__ dWhh,
                    const float* __restrict__ ddw,  const float* __restrict__ fcw)
{
    const int gid = blockIdx.x * blockDim.x + threadIdx.x;
    const int stride = gridDim.x * blockDim.x;
    for (int i = gid; i < BB*LK*FF; i += stride) g_xbf[i] = f2b(x[i]);
    for (int i = gid; i < LK*64*192; i += stride) {
        int t = i / 12288, rm = i % 12288, c = rm / 192, k = rm % 192;
        g_awT[i] = f2b(aw[((size_t)t*192 + k)*64 + c]);
    }
    for (int i = gid; i < 512*192; i += stride) {
        int j = i / 192, k = i % 192;
        g_eW[i] = f2b(k < 64 ? eWih[j*64 + k] : eWhh[j*128 + (k-64)]);
    }
    for (int i = gid; i < 512*384; i += stride) {
        int j = i / 384, k = i % 384;
        g_dW[i] = f2b(k < 256 ? dWih[j*256 + k] : dWhh[j*128 + (k-256)]);
    }
    for (int i = gid; i < NOUT*128*256; i += stride) {
        int s = i / 32768, rm = i % 32768, n = rm / 256, k = rm % 256;
        g_ddwT[i] = f2b(ddw[((size_t)s*256 + k)*128 + n]);
    }
    for (int i = gid; i < NOUT*64*128; i += stride) {
        int s = i / 8192, rm = i % 8192, n = rm / 128, k = rm % 128;
        g_fcwT[i] = f2b(fcw[((size_t)s*128 + k)*64 + n]);
    }
}

// chunk(32-wide) -> B k-offset for A=[x(64)|h_hi(128)|h_lo(128)] vs B=[x(64)|h(128)]
__device__ __forceinline__ int bk_enc(int c) { return c < 2 ? c*32 : 64 + ((c-2)&3)*32; }

__global__ __launch_bounds__(NTHR)
void darnn_kernel(const float* __restrict__ ab,
                  const float* __restrict__ ebih, const float* __restrict__ ebhh,
                  const float* __restrict__ dbih, const float* __restrict__ dbhh,
                  const float* __restrict__ ddb,
                  const float* __restrict__ dlw,  const float* __restrict__ dlb,
                  const float* __restrict__ fcb,
                  const float* __restrict__ ow,   const float* __restrict__ ob,
                  float* __restrict__ out)
{
    // A-tiles: rows 8..15 stay zero forever
    __shared__ u16  s_Ax [16][328];  // [xt(0:64) | h_hi(64:192) | h_lo(192:320)]
    __shared__ u16  s_Ain[16][328];  // [xin(0:64)| h_hi(64:192) | h_lo(192:320)]
    __shared__ u16  s_Adec[16][520]; // [ctx_hi(0:128)|ctx_lo(128:256)|h_hi(256:384)|h_lo(384:512)]
    __shared__ float s_e[8][64];     // attn pre-tanh scores
    __shared__ float s_g[512*9];     // gate pre-activations, pitch 9
    __shared__ float s_c[8][128];    // cell state fp32
    __shared__ float s_hp[8][128];   // decoder hpart
    __shared__ float s_spart[4][400];// score partials
    __shared__ float s_alpha[8][64]; // temporal attn weights
    __shared__ float s_y1[8][64];    // head intermediate
    __shared__ float s_ebias[512];
    __shared__ float s_dbias[512];

    const int tid  = threadIdx.x;
    const int b0   = blockIdx.x * BT;
    const int wv   = tid >> 6;
    const int lane = tid & 63;
    const int quad = lane >> 4;
    const int l16  = lane & 15;

    // init
    for (int i = tid; i < 16*328; i += NTHR) { (&s_Ax[0][0])[i] = 0; (&s_Ain[0][0])[i] = 0; }
    for (int i = tid; i < 16*520; i += NTHR) (&s_Adec[0][0])[i] = 0;
    (&s_c[0][0])[tid] = 0.0f;
    if (tid < 512) { s_ebias[tid] = ebih[tid] + ebhh[tid]; s_dbias[tid] = dbih[tid] + dbhh[tid]; }
    __syncthreads();

    // ================= ENCODER (R3 structure, 5 barriers/step) =================
#pragma unroll 1
    for (int t = 0; t < LK; ++t) {
        // E1: stage x_t (bf16)
        if (tid < 512) {
            int r = tid >> 6, f = tid & 63;
            s_Ax[r][f] = g_xbf[((size_t)(b0 + r) * LK + t) * FF + f];
        }
        __syncthreads();

        // E2: attention GEMM [16, 320-A] x [192-B, 64] — 4 waves, one 16-col tile each
        if (wv < 4) {
            f32x4 acc = {0.f, 0.f, 0.f, 0.f};
            const int f = wv * 16 + l16;
            const u16* bp = g_awT + (size_t)t * 64 * 192 + f * 192 + quad * 8;
#pragma unroll
            for (int c = 0; c < 10; ++c) {
                short8 av = *(const short8*)&s_Ax[l16][c*32 + quad*8];
                short8 bv = *(const short8*)(bp + bk_enc(c));
                acc = MFMA16(av, bv, acc);
            }
            float abv = ab[t * FF + f];
            if (quad < 2) {
#pragma unroll
                for (int rg = 0; rg < 4; ++rg) s_e[quad * 4 + rg][f] = acc[rg] + abv;
            }
        }
        __syncthreads();

        // E3: softmax over 64 features (wave per row); xin = softmax(tanh(e)) * xt
        if (tid < 512) {
            const int r = tid >> 6;
            float e = tanhff(s_e[r][lane]);
            float mx = e;
#pragma unroll
            for (int m = 1; m < 64; m <<= 1) mx = fmaxf(mx, __shfl_xor(mx, m, 64));
            float ex = __expf(e - mx);
            float sm = ex;
#pragma unroll
            for (int m = 1; m < 64; m <<= 1) sm += __shfl_xor(sm, m, 64);
            s_Ain[r][lane] = f2b(ex / sm * b2f(s_Ax[r][lane]));
        }
        __syncthreads();

        // E4: LSTM gate GEMM [16, 320-A] x [192-B, 512] — 16 waves x 2 col-tiles
        {
            const int n0 = wv * 32;
            f32x4 a0 = {0.f,0.f,0.f,0.f}, a1 = {0.f,0.f,0.f,0.f};
            const u16* bp0 = g_eW + (n0 + l16) * 192 + quad * 8;
            const u16* bp1 = bp0 + 16 * 192;
#pragma unroll
            for (int c = 0; c < 10; ++c) {
                const int bo = bk_enc(c);
                short8 av = *(const short8*)&s_Ain[l16][c*32 + quad*8];
                a0 = MFMA16(av, *(const short8*)(bp0 + bo), a0);
                a1 = MFMA16(av, *(const short8*)(bp1 + bo), a1);
            }
            if (quad < 2) {
#pragma unroll
                for (int rg = 0; rg < 4; ++rg) {
                    int r = quad * 4 + rg;
                    s_g[(n0 + l16) * 9 + r]      = a0[rg];
                    s_g[(n0 + 16 + l16) * 9 + r] = a1[rg];
                }
            }
        }
        __syncthreads();

        // E5: gate combine + state update (hi/lo) + enc store
        {
            const int u = tid & 127, r = tid >> 7;
            float gi = s_g[u * 9 + r]         + s_ebias[u];
            float gf = s_g[(128 + u) * 9 + r] + s_ebias[128 + u];
            float gg = s_g[(256 + u) * 9 + r] + s_ebias[256 + u];
            float go = s_g[(384 + u) * 9 + r] + s_ebias[384 + u];
            float c = sigf(gf) * s_c[r][u] + sigf(gi) * tanhff(gg);
            float h = sigf(go) * tanhff(c);
            s_c[r][u] = c;
            u16 hi = f2b(h);
            u16 lo = f2b(h - b2f(hi));
            s_Ax[r][64 + u]   = hi;  s_Ax[r][192 + u]  = lo;
            s_Ain[r][64 + u]  = hi;  s_Ain[r][192 + u] = lo;
            size_t eb = ((size_t)(b0 + r) * LK + t) * 256;
            g_encbf[eb + u]       = hi;
            g_encbf[eb + 128 + u] = lo;
        }
        __syncthreads();
    }

    // ================= DECODER: 3 steps =================
    (&s_c[0][0])[tid] = 0.0f;   // s_Adec still zero from init
    __syncthreads();

#pragma unroll 1
    for (int s = 0; s < NOUT; ++s) {
        // D1: hpart = h_de(hi/lo) @ ddw[128:,:] + ddb  (8 waves)
        if (wv < 8) {
            const int n = wv * 16 + l16;
            f32x4 acc = {0.f,0.f,0.f,0.f};
            const u16* bp = g_ddwT + s * 32768 + n * 256 + 128 + quad * 8;
#pragma unroll
            for (int c = 0; c < 8; ++c) {
                short8 av = *(const short8*)&s_Adec[l16][256 + c*32 + quad*8];
                acc = MFMA16(av, *(const short8*)(bp + (c&3)*32), acc);
            }
            float db = ddb[s * 128 + n];
            if (quad < 2) {
#pragma unroll
                for (int rg = 0; rg < 4; ++rg) s_hp[quad*4 + rg][n] = acc[rg] + db;
            }
        }
        __syncthreads();

        // D2: score GEMM [400, 256-A(hi/lo)] x [128-B, 128]
        {
            const int np = wv & 3, mq = wv >> 2, nb0 = np * 32;
            short8 bfr[8];
            const u16* bp = g_ddwT + s * 32768 + (nb0 + l16) * 256 + quad * 8;
#pragma unroll
            for (int nn = 0; nn < 2; ++nn)
#pragma unroll
                for (int ks = 0; ks < 4; ++ks)
                    bfr[nn*4+ks] = *(const short8*)(bp + nn*4096 + ks*32);
            const float dl0 = dlw[s*128 + nb0 + l16];
            const float dl1 = dlw[s*128 + nb0 + 16 + l16];
#pragma unroll 1
            for (int mt = mq; mt < 25; mt += 4) {
                const u16* ap = g_encbf + ((size_t)b0 * LK + mt*16 + l16) * 256 + quad * 8;
                f32x4 a0 = {0.f,0.f,0.f,0.f}, a1 = {0.f,0.f,0.f,0.f};
#pragma unroll
                for (int c = 0; c < 8; ++c) {
                    short8 av = *(const short8*)(ap + c*32);
                    a0 = MFMA16(av, bfr[c&3],     a0);
                    a1 = MFMA16(av, bfr[4+(c&3)], a1);
                }
#pragma unroll
                for (int rg = 0; rg < 4; ++rg) {
                    int rt = mt*16 + quad*4 + rg;
                    int r  = rt / LK;
                    float v = tanhff(a0[rg] + s_hp[r][nb0 + l16]) * dl0
                            + tanhff(a1[rg] + s_hp[r][nb0 + 16 + l16]) * dl1;
                    v += __shfl_xor(v, 1, 64); v += __shfl_xor(v, 2, 64);
                    v += __shfl_xor(v, 4, 64); v += __shfl_xor(v, 8, 64);
                    if (l16 == 0) s_spart[np][rt] = v;
                }
            }
        }
        __syncthreads();

        // D3: softmax over t (wave per row)
        if (tid < 512) {
            const int r = tid >> 6;
            float sv = (lane < LK)
                ? (s_spart[0][r*LK + lane] + s_spart[1][r*LK + lane] +
                   s_spart[2][r*LK + lane] + s_spart[3][r*LK + lane] + dlb[s])
                : -1e30f;
            float mx = sv;
#pragma unroll
            for (int m = 1; m < 64; m <<= 1) mx = fmaxf(mx, __shfl_xor(mx, m, 64));
            float ex = (lane < LK) ? __expf(sv - mx) : 0.0f;
            float sm = ex;
#pragma unroll
            for (int m = 1; m < 64; m <<= 1) sm += __shfl_xor(sm, m, 64);
            if (lane < LK) s_alpha[r][lane] = ex / sm;
        }
        __syncthreads();

        // D4: ctx = sum_t alpha * (enc_hi + enc_lo) in fp32; store ctx hi/lo
        {
            const int jd = tid & 127, r = tid >> 7;
            const u16* ep = g_encbf + (size_t)(b0 + r) * LK * 256 + jd;
            float a = 0.0f;
#pragma unroll 10
            for (int tt = 0; tt < LK; ++tt)
                a += s_alpha[r][tt] * (b2f(ep[tt*256]) + b2f(ep[tt*256 + 128]));
            u16 hi = f2b(a);
            s_Adec[r][jd]       = hi;
            s_Adec[r][128 + jd] = f2b(a - b2f(hi));
        }
        __syncthreads();

        // D5: decoder LSTM gates [16, 768-A(hi/lo)] x [384-B, 512] — full K per wave
        {
            const int n0 = wv * 32;
            f32x4 a0 = {0.f,0.f,0.f,0.f}, a1 = {0.f,0.f,0.f,0.f};
            const u16* bp0 = g_dW + (n0 + l16) * 384 + quad * 8;
            const u16* bp1 = bp0 + 16 * 384;
#pragma unroll
            for (int c = 0; c < 24; ++c) {
                const int g = c >> 2, o = (c & 3) * 32;
                const int ao = (g < 2 ? g*128 : 256 + (g & 1)*128) + o;  // A col
                const int bo = ((g >> 1) << 7) + o;                       // B k-offset
                short8 av = *(const short8*)&s_Adec[l16][ao + quad*8];
                a0 = MFMA16(av, *(const short8*)(bp0 + bo), a0);
                a1 = MFMA16(av, *(const short8*)(bp1 + bo), a1);
            }
            if (quad < 2) {
#pragma unroll
                for (int rg = 0; rg < 4; ++rg) {
                    int r = quad*4 + rg;
                    s_g[(n0 + l16) * 9 + r]      = a0[rg];
                    s_g[(n0 + 16 + l16) * 9 + r] = a1[rg];
                }
            }
        }
        __syncthreads();

        // D6: gate combine + state update (hi/lo)
        {
            const int u = tid & 127, r = tid >> 7;
            float gi = s_g[u * 9 + r]         + s_dbias[u];
            float gf = s_g[(128 + u) * 9 + r] + s_dbias[128 + u];
            float gg = s_g[(256 + u) * 9 + r] + s_dbias[256 + u];
            float go = s_g[(384 + u) * 9 + r] + s_dbias[384 + u];
            float c = sigf(gf) * s_c[r][u] + sigf(gi) * tanhff(gg);
            float h = sigf(go) * tanhff(c);
            s_c[r][u] = c;
            u16 hi = f2b(h);
            s_Adec[r][256 + u] = hi;
            s_Adec[r][384 + u] = f2b(h - b2f(hi));
        }
        __syncthreads();

        // D7: head y1 = tanh(h(hi/lo) @ fc_w + fc_b) (4 waves)
        if (wv < 4) {
            const int n = wv * 16 + l16;
            f32x4 acc = {0.f,0.f,0.f,0.f};
            const u16* bp = g_fcwT + s * 8192 + n * 128 + quad * 8;
#pragma unroll
            for (int c = 0; c < 8; ++c) {
                short8 av = *(const short8*)&s_Adec[l16][256 + c*32 + quad*8];
                acc = MFMA16(av, *(const short8*)(bp + (c&3)*32), acc);
            }
            float fb = fcb[s * 64 + n];
            if (quad < 2) {
#pragma unroll
                for (int rg = 0; rg < 4; ++rg) s_y1[quad*4 + rg][n] = tanhff(acc[rg] + fb);
            }
        }
        __syncthreads();

        // D8: out = sigmoid(y1 @ out_w + out_b)
        if (tid < 512) {
            const int r = tid >> 6;
            float v = s_y1[r][lane] * ow[s * 64 + lane];
#pragma unroll
            for (int m = 1; m < 64; m <<= 1) v += __shfl_xor(v, m, 64);
            if (lane == 0) out[(b0 + r) * NOUT + s] = sigf(v + ob[s]);
        }
        __syncthreads();
    }
}

extern "C" void kernel_launch(void* const* d_in, const int* in_sizes, int n_in,
                              void* d_out, int out_size, void* d_ws, size_t ws_size,
                              hipStream_t stream) {
    const float* x    = (const float*)d_in[0];
    const float* eWih = (const float*)d_in[1];
    const float* eWhh = (const float*)d_in[2];
    const float* ebih = (const float*)d_in[3];
    const float* ebhh = (const float*)d_in[4];
    const float* aw   = (const float*)d_in[5];
    const float* ab   = (const float*)d_in[6];
    const float* dWih = (const float*)d_in[7];
    const float* dWhh = (const float*)d_in[8];
    const float* dbih = (const float*)d_in[9];
    const float* dbhh = (const float*)d_in[10];
    const float* ddw  = (const float*)d_in[11];
    const float* ddb  = (const float*)d_in[12];
    const float* dlw  = (const float*)d_in[13];
    const float* dlb  = (const float*)d_in[14];
    const float* fcw  = (const float*)d_in[15];
    const float* fcb  = (const float*)d_in[16];
    const float* ow   = (const float*)d_in[17];
    const float* ob   = (const float*)d_in[18];
    float* out = (float*)d_out;

    convert_kernel<<<4096, 256, 0, stream>>>(x, eWih, eWhh, aw, dWih, dWhh, ddw, fcw);
    darnn_kernel<<<NWG, NTHR, 0, stream>>>(ab, ebih, ebhh, dbih, dbhh, ddb,
                                           dlw, dlb, fcb, ow, ob, out);
}

// Round 7
// 493.685 us; speedup vs baseline: 1.3556x; 1.3556x over previous
//
#include <hip/hip_runtime.h>

#define LK   50      // look_back
#define NOUT 3
#define FF   64      // feature_num
#define BB   2048    // batch
#define HH   128     // units
#define BT   8       // batch rows per workgroup
#define NWG  (BB/BT) // 256 workgroups
#define NTHR 1024    // 16 waves

typedef unsigned short u16;
typedef unsigned int   u32;
typedef __attribute__((ext_vector_type(8))) short short8;
typedef __attribute__((ext_vector_type(4))) float f32x4;

#define MFMA16(a,b,c) __builtin_amdgcn_mfma_f32_16x16x32_bf16(a,b,c,0,0,0)

// pre-converted bf16 buffers (device globals; rewritten every launch)
__device__ u16 g_xbf [(size_t)BB*LK*FF];   // x,        [b][t][f]
__device__ u16 g_awT [(size_t)LK*64*192];  // attn_w^T, [t][c][k]  k:[xt(64)|h(128)]
__device__ u16 g_eW  [512*192];            // enc LSTM, [gate][k]  k:[xin(64)|h(128)]
__device__ u16 g_dW  [512*384];            // dec LSTM, [gate][k]  k:[ctx(128)|h(128)|h(128)]
__device__ u16 g_ddwT[NOUT*128*256];       // dd_w^T,   [s][n][k]  k:[enc(128)|h(128)]
__device__ u16 g_fcwT[NOUT*64*128];        // fc_w^T,   [s][n][k]
__device__ u16 g_encbf[(size_t)BB*LK*256]; // encoder outputs hi/lo: [b][t][hi(128)|lo(128)]

__device__ __forceinline__ float sigf(float x) { return 1.0f / (1.0f + __expf(-x)); }
__device__ __forceinline__ float tanhff(float x) { return 1.0f - 2.0f / (__expf(2.0f * x) + 1.0f); }
__device__ __forceinline__ u16 f2b(float f) {
    union { float f; u32 u; } v; v.f = f;
    u32 r = v.u + 0x7fffu + ((v.u >> 16) & 1u);
    return (u16)(r >> 16);
}
__device__ __forceinline__ float b2f(u16 h) {
    union { u32 u; float f; } v; v.u = ((u32)h) << 16; return v.f;
}

// coalesced-read convert (layouts identical to R3/R6's verified version)
__global__ __launch_bounds__(256)
void convert_kernel(const float* __restrict__ x,
                    const float* __restrict__ eWih, const float* __restrict__ eWhh,
                    const float* __restrict__ aw,
                    const float* __restrict__ dWih, const float* __restrict__ dWhh,
                    const float* __restrict__ ddw,  const float* __restrict__ fcw)
{
    const int gid = blockIdx.x * blockDim.x + threadIdx.x;
    const int stride = gridDim.x * blockDim.x;
    {
        const float2* xs = (const float2*)x;
        u32* xd = (u32*)g_xbf;
        for (int i = gid; i < BB*LK*FF/2; i += stride) {
            float2 v = xs[i];
            xd[i] = (u32)f2b(v.x) | ((u32)f2b(v.y) << 16);
        }
    }
    // awT: iterate SOURCE-major (coalesced reads), scattered u16 writes
    for (int i = gid; i < LK*192*64; i += stride) {
        int t = i / 12288, rm = i % 12288, k = rm / 64, c = rm % 64;
        g_awT[(size_t)t*12288 + c*192 + k] = f2b(aw[i]);
    }
    for (int i = gid; i < 512*192; i += stride) {
        int j = i / 192, k = i % 192;
        g_eW[i] = f2b(k < 64 ? eWih[j*64 + k] : eWhh[j*128 + (k-64)]);
    }
    for (int i = gid; i < 512*384; i += stride) {
        int j = i / 384, k = i % 384;
        g_dW[i] = f2b(k < 256 ? dWih[j*256 + k] : dWhh[j*128 + (k-256)]);
    }
    for (int i = gid; i < NOUT*256*128; i += stride) {
        int s = i / 32768, rm = i % 32768, k = rm / 128, n = rm % 128;
        g_ddwT[(size_t)s*32768 + n*256 + k] = f2b(ddw[i]);
    }
    for (int i = gid; i < NOUT*128*64; i += stride) {
        int s = i / 8192, rm = i % 8192, k = rm / 64, n = rm % 64;
        g_fcwT[(size_t)s*8192 + n*128 + k] = f2b(fcw[i]);
    }
}

// chunk(32-wide) -> B k-offset for A=[x(64)|h_hi(128)|h_lo(128)] vs B=[x(64)|h(128)]
__device__ __forceinline__ int bk_enc(int c) { return c < 2 ? c*32 : 64 + ((c-2)&3)*32; }

__global__ __launch_bounds__(NTHR, 4)
void darnn_kernel(const float* __restrict__ ab,
                  const float* __restrict__ ebih, const float* __restrict__ ebhh,
                  const float* __restrict__ dbih, const float* __restrict__ dbhh,
                  const float* __restrict__ ddb,
                  const float* __restrict__ dlw,  const float* __restrict__ dlb,
                  const float* __restrict__ fcb,
                  const float* __restrict__ ow,   const float* __restrict__ ob,
                  float* __restrict__ out)
{
    __shared__ u16  s_awT[2][64][200];  // double-buffered attn B; per-t slice = 6144 DWORDS
    __shared__ u16  s_A[16][328];       // [xt/xin(0:64)|h_hi(64:192)|h_lo(192:320)], rows 8..15 zero
    __shared__ u16  s_Adec[16][520];    // [ctx_hi|ctx_lo|h_hi(256:384)|h_lo(384:512)]
    __shared__ float s_g[2][512][9];    // gate partials (kg halves; decoder uses [0] only)
    __shared__ float s_c[8][128];       // cell state fp32
    __shared__ float s_hp[8][128];      // decoder hpart
    __shared__ float s_spart[4][400];   // score partials
    __shared__ float s_alpha[8][64];    // temporal attn weights
    __shared__ float s_y1[8][64];       // head intermediate
    __shared__ float s_ebias[512];
    __shared__ float s_dbias[512];

    const int tid  = threadIdx.x;
    const int b0   = blockIdx.x * BT;
    const int wv   = tid >> 6;
    const int lane = tid & 63;
    const int quad = lane >> 4;
    const int l16  = lane & 15;
    const int ntp  = wv & 7;            // n-tile pair for encoder gate GEMM
    const int kg   = wv >> 3;           // K-group (0/1)
    const int n0e  = ntp * 32;

    // ---- preamble ----
    for (int i = tid; i < 16*328; i += NTHR) (&s_A[0][0])[i] = 0;
    for (int i = tid; i < 16*520; i += NTHR) (&s_Adec[0][0])[i] = 0;
    (&s_c[0][0])[tid] = 0.0f;
    if (tid < 512) { s_ebias[tid] = ebih[tid] + ebhh[tid]; s_dbias[tid] = dbih[tid] + dbhh[tid]; }
    if (tid < 512) {
        int r = tid >> 6, f = tid & 63;
        s_A[r][f] = g_xbf[((size_t)(b0 + r) * LK + 0) * FF + f];
    }
    {   // stage awT[0] into buffer 0: per-t slice = 64 rows x 96 dwords = 6144 dwords
        const u32* src = (const u32*)g_awT;
        u32* dst = (u32*)&s_awT[0][0][0];
#pragma unroll
        for (int j = 0; j < 6; ++j) {
            int d = j * 1024 + tid;          // d < 6144 always
            u32 v = src[d];
            int c = d / 96, k2 = d - c * 96;
            dst[c * 100 + k2] = v;
        }
    }
    // encoder LSTM B-fragments pinned in registers (2 n-tiles x 5 K-chunks = 40 VGPRs)
    short8 wf[10];
#pragma unroll
    for (int nn = 0; nn < 2; ++nn)
#pragma unroll
        for (int i = 0; i < 5; ++i) {
            const int c = kg * 5 + i;
            wf[nn*5+i] = *(const short8*)(g_eW + (n0e + nn*16 + l16) * 192 + bk_enc(c) + quad*8);
        }
    __syncthreads();

    // ================= ENCODER: 50 steps, 3 barriers each =================
#pragma unroll 1
    for (int t = 0; t < LK; ++t) {
        // --- phase 1: waves 1-15 stage awT[t+1]; wave 0: attention + softmax ---
        if (wv > 0) {
            if (t + 1 < LK) {
                const u32* src = (const u32*)g_awT + (size_t)(t + 1) * 6144;
                u32* dst = (u32*)&s_awT[(t + 1) & 1][0][0];
                const int l9 = tid - 64;     // 0..959
#pragma unroll
                for (int j = 0; j < 7; ++j) {
                    int d = j * 960 + l9;
                    if (d < 6144) {
                        u32 v = src[d];
                        int c = d / 96, k2 = d - c * 96;
                        dst[c * 100 + k2] = v;
                    }
                }
            }
        } else {
            // attention GEMM [16,320-A]x[192-B,64] in one wave, 4 col-tiles in-lane
            const u16* bw = &s_awT[t & 1][0][0];
            f32x4 acc[4];
#pragma unroll
            for (int ft = 0; ft < 4; ++ft) acc[ft] = (f32x4){0.f,0.f,0.f,0.f};
#pragma unroll
            for (int c = 0; c < 10; ++c) {
                const int bo = bk_enc(c) + quad*8;
                short8 av = *(const short8*)&s_A[l16][c*32 + quad*8];
#pragma unroll
                for (int ft = 0; ft < 4; ++ft)
                    acc[ft] = MFMA16(av, *(const short8*)(bw + (ft*16 + l16)*200 + bo), acc[ft]);
            }
            float e[4][4];
#pragma unroll
            for (int ft = 0; ft < 4; ++ft) {
                float abv = ab[t * FF + ft*16 + l16];
#pragma unroll
                for (int rg = 0; rg < 4; ++rg) e[ft][rg] = tanhff(acc[ft][rg] + abv);
            }
            float ex[4][4], inv[4];
#pragma unroll
            for (int rg = 0; rg < 4; ++rg) {
                float m = fmaxf(fmaxf(e[0][rg], e[1][rg]), fmaxf(e[2][rg], e[3][rg]));
                m = fmaxf(m, __shfl_xor(m, 1, 16)); m = fmaxf(m, __shfl_xor(m, 2, 16));
                m = fmaxf(m, __shfl_xor(m, 4, 16)); m = fmaxf(m, __shfl_xor(m, 8, 16));
                float sm = 0.f;
#pragma unroll
                for (int ft = 0; ft < 4; ++ft) { ex[ft][rg] = __expf(e[ft][rg] - m); sm += ex[ft][rg]; }
                sm += __shfl_xor(sm, 1, 16); sm += __shfl_xor(sm, 2, 16);
                sm += __shfl_xor(sm, 4, 16); sm += __shfl_xor(sm, 8, 16);
                inv[rg] = 1.0f / sm;
            }
            if (quad < 2) {
#pragma unroll
                for (int ft = 0; ft < 4; ++ft)
#pragma unroll
                    for (int rg = 0; rg < 4; ++rg) {
                        int row = quad*4 + rg, col = ft*16 + l16;
                        float xt = b2f(s_A[row][col]);
                        s_A[row][col] = f2b(ex[ft][rg] * inv[rg] * xt);
                    }
            }
        }
        __syncthreads();

        // --- phase 2: gate GEMM [16,320-A]x[192-B,512], K-split, B pinned ---
        {
            f32x4 a0 = {0.f,0.f,0.f,0.f}, a1 = {0.f,0.f,0.f,0.f};
#pragma unroll
            for (int i = 0; i < 5; ++i) {
                const int c = kg * 5 + i;
                short8 av = *(const short8*)&s_A[l16][c*32 + quad*8];
                a0 = MFMA16(av, wf[i],   a0);
                a1 = MFMA16(av, wf[5+i], a1);
            }
            if (quad < 2) {
#pragma unroll
                for (int rg = 0; rg < 4; ++rg) {
                    int r = quad*4 + rg;
                    s_g[kg][n0e + l16][r]      = a0[rg];
                    s_g[kg][n0e + 16 + l16][r] = a1[rg];
                }
            }
        }
        __syncthreads();

        // --- phase 3: gate combine + state update (hi/lo) + enc store + x prefetch ---
        {
            const int u = tid & 127, r = tid >> 7;
            float gi = s_g[0][u][r]     + s_g[1][u][r]     + s_ebias[u];
            float gf = s_g[0][128+u][r] + s_g[1][128+u][r] + s_ebias[128+u];
            float gg = s_g[0][256+u][r] + s_g[1][256+u][r] + s_ebias[256+u];
            float go = s_g[0][384+u][r] + s_g[1][384+u][r] + s_ebias[384+u];
            float c = sigf(gf) * s_c[r][u] + sigf(gi) * tanhff(gg);
            float h = sigf(go) * tanhff(c);
            s_c[r][u] = c;
            u16 hi = f2b(h);
            u16 lo = f2b(h - b2f(hi));
            s_A[r][64 + u]  = hi;
            s_A[r][192 + u] = lo;
            size_t eb = ((size_t)(b0 + r) * LK + t) * 256;
            g_encbf[eb + u]       = hi;
            g_encbf[eb + 128 + u] = lo;
        }
        if (tid < 512 && t + 1 < LK) {
            int r = tid >> 6, f = tid & 63;
            s_A[r][f] = g_xbf[((size_t)(b0 + r) * LK + (t + 1)) * FF + f];
        }
        __syncthreads();
    }

    // ================= DECODER: 3 steps (R6 verbatim; s_g[0] region) =================
    (&s_c[0][0])[tid] = 0.0f;   // s_Adec still zero from init
    __syncthreads();

#pragma unroll 1
    for (int s = 0; s < NOUT; ++s) {
        // D1: hpart = h_de(hi/lo) @ ddw[128:,:] + ddb  (8 waves)
        if (wv < 8) {
            const int n = wv * 16 + l16;
            f32x4 acc = {0.f,0.f,0.f,0.f};
            const u16* bp = g_ddwT + s * 32768 + n * 256 + 128 + quad * 8;
#pragma unroll
            for (int c = 0; c < 8; ++c) {
                short8 av = *(const short8*)&s_Adec[l16][256 + c*32 + quad*8];
                acc = MFMA16(av, *(const short8*)(bp + (c&3)*32), acc);
            }
            float db = ddb[s * 128 + n];
            if (quad < 2) {
#pragma unroll
                for (int rg = 0; rg < 4; ++rg) s_hp[quad*4 + rg][n] = acc[rg] + db;
            }
        }
        __syncthreads();

        // D2: score GEMM [400, 256-A(hi/lo)] x [128-B, 128]
        {
            const int np = wv & 3, mq = wv >> 2, nb0 = np * 32;
            short8 bfr[8];
            const u16* bp = g_ddwT + s * 32768 + (nb0 + l16) * 256 + quad * 8;
#pragma unroll
            for (int nn = 0; nn < 2; ++nn)
#pragma unroll
                for (int ks = 0; ks < 4; ++ks)
                    bfr[nn*4+ks] = *(const short8*)(bp + nn*4096 + ks*32);
            const float dl0 = dlw[s*128 + nb0 + l16];
            const float dl1 = dlw[s*128 + nb0 + 16 + l16];
#pragma unroll 1
            for (int mt = mq; mt < 25; mt += 4) {
                const u16* ap = g_encbf + ((size_t)b0 * LK + mt*16 + l16) * 256 + quad * 8;
                f32x4 a0 = {0.f,0.f,0.f,0.f}, a1 = {0.f,0.f,0.f,0.f};
#pragma unroll
                for (int c = 0; c < 8; ++c) {
                    short8 av = *(const short8*)(ap + c*32);
                    a0 = MFMA16(av, bfr[c&3],     a0);
                    a1 = MFMA16(av, bfr[4+(c&3)], a1);
                }
#pragma unroll
                for (int rg = 0; rg < 4; ++rg) {
                    int rt = mt*16 + quad*4 + rg;
                    int r  = rt / LK;
                    float v = tanhff(a0[rg] + s_hp[r][nb0 + l16]) * dl0
                            + tanhff(a1[rg] + s_hp[r][nb0 + 16 + l16]) * dl1;
                    v += __shfl_xor(v, 1, 64); v += __shfl_xor(v, 2, 64);
                    v += __shfl_xor(v, 4, 64); v += __shfl_xor(v, 8, 64);
                    if (l16 == 0) s_spart[np][rt] = v;
                }
            }
        }
        __syncthreads();

        // D3: softmax over t (wave per row)
        if (tid < 512) {
            const int r = tid >> 6;
            float sv = (lane < LK)
                ? (s_spart[0][r*LK + lane] + s_spart[1][r*LK + lane] +
                   s_spart[2][r*LK + lane] + s_spart[3][r*LK + lane] + dlb[s])
                : -1e30f;
            float mx = sv;
#pragma unroll
            for (int m = 1; m < 64; m <<= 1) mx = fmaxf(mx, __shfl_xor(mx, m, 64));
            float ex = (lane < LK) ? __expf(sv - mx) : 0.0f;
            float sm = ex;
#pragma unroll
            for (int m = 1; m < 64; m <<= 1) sm += __shfl_xor(sm, m, 64);
            if (lane < LK) s_alpha[r][lane] = ex / sm;
        }
        __syncthreads();

        // D4: ctx = sum_t alpha * (enc_hi + enc_lo) in fp32; store ctx hi/lo
        {
            const int jd = tid & 127, r = tid >> 7;
            const u16* ep = g_encbf + (size_t)(b0 + r) * LK * 256 + jd;
            float a = 0.0f;
#pragma unroll 10
            for (int tt = 0; tt < LK; ++tt)
                a += s_alpha[r][tt] * (b2f(ep[tt*256]) + b2f(ep[tt*256 + 128]));
            u16 hi = f2b(a);
            s_Adec[r][jd]       = hi;
            s_Adec[r][128 + jd] = f2b(a - b2f(hi));
        }
        __syncthreads();

        // D5: decoder LSTM gates [16, 768-A(hi/lo)] x [384-B, 512] — full K per wave
        {
            const int n0 = wv * 32;
            f32x4 a0 = {0.f,0.f,0.f,0.f}, a1 = {0.f,0.f,0.f,0.f};
            const u16* bp0 = g_dW + (n0 + l16) * 384 + quad * 8;
            const u16* bp1 = bp0 + 16 * 384;
#pragma unroll
            for (int c = 0; c < 24; ++c) {
                const int g = c >> 2, o = (c & 3) * 32;
                const int ao = (g < 2 ? g*128 : 256 + (g & 1)*128) + o;  // A col
                const int bo = ((g >> 1) << 7) + o;                       // B k-offset
                short8 av = *(const short8*)&s_Adec[l16][ao + quad*8];
                a0 = MFMA16(av, *(const short8*)(bp0 + bo), a0);
                a1 = MFMA16(av, *(const short8*)(bp1 + bo), a1);
            }
            if (quad < 2) {
#pragma unroll
                for (int rg = 0; rg < 4; ++rg) {
                    int r = quad*4 + rg;
                    s_g[0][n0 + l16][r]      = a0[rg];
                    s_g[0][n0 + 16 + l16][r] = a1[rg];
                }
            }
        }
        __syncthreads();

        // D6: gate combine + state update (hi/lo)
        {
            const int u = tid & 127, r = tid >> 7;
            float gi = s_g[0][u][r]       + s_dbias[u];
            float gf = s_g[0][128 + u][r] + s_dbias[128 + u];
            float gg = s_g[0][256 + u][r] + s_dbias[256 + u];
            float go = s_g[0][384 + u][r] + s_dbias[384 + u];
            float c = sigf(gf) * s_c[r][u] + sigf(gi) * tanhff(gg);
            float h = sigf(go) * tanhff(c);
            s_c[r][u] = c;
            u16 hi = f2b(h);
            s_Adec[r][256 + u] = hi;
            s_Adec[r][384 + u] = f2b(h - b2f(hi));
        }
        __syncthreads();

        // D7: head y1 = tanh(h(hi/lo) @ fc_w + fc_b) (4 waves)
        if (wv < 4) {
            const int n = wv * 16 + l16;
            f32x4 acc = {0.f,0.f,0.f,0.f};
            const u16* bp = g_fcwT + s * 8192 + n * 128 + quad * 8;
#pragma unroll
            for (int c = 0; c < 8; ++c) {
                short8 av = *(const short8*)&s_Adec[l16][256 + c*32 + quad*8];
                acc = MFMA16(av, *(const short8*)(bp + (c&3)*32), acc);
            }
            float fb = fcb[s * 64 + n];
            if (quad < 2) {
#pragma unroll
                for (int rg = 0; rg < 4; ++rg) s_y1[quad*4 + rg][n] = tanhff(acc[rg] + fb);
            }
        }
        __syncthreads();

        // D8: out = sigmoid(y1 @ out_w + out_b)
        if (tid < 512) {
            const int r = tid >> 6;
            float v = s_y1[r][lane] * ow[s * 64 + lane];
#pragma unroll
            for (int m = 1; m < 64; m <<= 1) v += __shfl_xor(v, m, 64);
            if (lane == 0) out[(b0 + r) * NOUT + s] = sigf(v + ob[s]);
        }
        __syncthreads();
    }
}

extern "C" void kernel_launch(void* const* d_in, const int* in_sizes, int n_in,
                              void* d_out, int out_size, void* d_ws, size_t ws_size,
                              hipStream_t stream) {
    const float* x    = (const float*)d_in[0];
    const float* eWih = (const float*)d_in[1];
    const float* eWhh = (const float*)d_in[2];
    const float* ebih = (const float*)d_in[3];
    const float* ebhh = (const float*)d_in[4];
    const float* aw   = (const float*)d_in[5];
    const float* ab   = (const float*)d_in[6];
    const float* dWih = (const float*)d_in[7];
    const float* dWhh = (const float*)d_in[8];
    const float* dbih = (const float*)d_in[9];
    const float* dbhh = (const float*)d_in[10];
    const float* ddw  = (const float*)d_in[11];
    const float* ddb  = (const float*)d_in[12];
    const float* dlw  = (const float*)d_in[13];
    const float* dlb  = (const float*)d_in[14];
    const float* fcw  = (const float*)d_in[15];
    const float* fcb  = (const float*)d_in[16];
    const float* ow   = (const float*)d_in[17];
    const float* ob   = (const float*)d_in[18];
    float* out = (float*)d_out;

    convert_kernel<<<1280, 256, 0, stream>>>(x, eWih, eWhh, aw, dWih, dWhh, ddw, fcw);
    darnn_kernel<<<NWG, NTHR, 0, stream>>>(ab, ebih, ebhh, dbih, dbhh, ddb,
                                           dlw, dlb, fcb, ow, ob, out);
}